// Round 10
// baseline (102.178 us; speedup 1.0000x reference)
//
#include <hip/hip_runtime.h>
#include <math.h>

#define F 128
#define HEADS 4
#define DHEAD 32
#define HIST_H 128         // segments per class; 8*HIST_H hist/scatter blocks
#define CW_MAX 6592        // max nodes per class (LDS cap); N <= 52736

typedef unsigned short ushort_t;
typedef unsigned long long u64_t;
typedef __attribute__((ext_vector_type(8))) short short8;   // 8 bf16 (4 VGPR)
typedef __attribute__((ext_vector_type(4))) float f32x4;    // MFMA acc

// round-to-nearest-even fp32 -> bf16
__device__ __forceinline__ ushort_t f2bf(float x) {
  unsigned u = __float_as_uint(x);
  unsigned r = u + 0x7FFFu + ((u >> 16) & 1u);
  return (ushort_t)(r >> 16);
}

// unpack 8 packed bf16 (as int4) -> 8 fp32
__device__ __forceinline__ void unpack8(const int4& r, float* v) {
  int rr[4] = {r.x, r.y, r.z, r.w};
#pragma unroll
  for (int q = 0; q < 4; q++) {
    unsigned u = (unsigned)rr[q];
    v[2 * q] = __uint_as_float(u << 16);
    v[2 * q + 1] = __uint_as_float(u & 0xFFFF0000u);
  }
}

// ---------------------------------------------------------------------------
// K-1: pack W into MFMA-fragment-ordered bf16 hi/lo arrays; block 0 also
// zeroes the scan lookback state (runs strictly before scan_kernel on stream).
// ---------------------------------------------------------------------------
__global__ __launch_bounds__(256) void wprep_kernel(
    const float* __restrict__ W, ushort_t* __restrict__ whi,
    ushort_t* __restrict__ wlo, u64_t* __restrict__ bstate) {
  if (blockIdx.x == 0) bstate[threadIdx.x] = 0ULL;
  int idx = blockIdx.x * 256 + threadIdx.x;  // 0..16383
  if (idx >= 128 * 128) return;
  int j = idx & 7;
  int lane = (idx >> 3) & 63;
  int f = idx >> 9;  // kt*8+nt
  int kt = f >> 3, nt = f & 7;
  int k = kt * 32 + (lane >> 4) * 8 + j;
  int n = nt * 16 + (lane & 15);
  float w = W[k * 128 + n];
  unsigned u = __float_as_uint(w);
  unsigned hb = u & 0xFFFF0000u;
  float lo = w - __uint_as_float(hb);
  whi[idx] = (ushort_t)(hb >> 16);
  wlo[idx] = f2bf(lo);
}

// ---------------------------------------------------------------------------
// K1: fused  [0..gemmBlocks): ft = feat @ W via split-precision bf16 MFMA
//            [gemmBlocks..+8*HIST_H): LDS partial histograms -> u16 partials.
// ---------------------------------------------------------------------------
__global__ __launch_bounds__(256) void gemm_hist_kernel(
    const float* __restrict__ feat, const ushort_t* __restrict__ whi,
    const ushort_t* __restrict__ wlo, ushort_t* __restrict__ ftb, int N,
    const int* __restrict__ dst, ushort_t* __restrict__ partials, int cwp,
    int E, int gemmBlocks) {
  __shared__ int lh[CW_MAX];
  if ((int)blockIdx.x >= gemmBlocks) {
    // ---- partial histogram path (LDS atomics only) ----
    const int hb = blockIdx.x - gemmBlocks;
    const int cls = hb & 7;
    const int h = hb >> 3;
    const int cw = (N + 7) >> 3;
    const int nbase = cls * cw;
    for (int j = threadIdx.x; j < cw; j += 256) lh[j] = 0;
    __syncthreads();
    const int seg = (E + HIST_H - 1) / HIST_H;
    const int e0 = h * seg;
    const int e1 = min(e0 + seg, E);
    int e = e0 + (int)threadIdx.x;
    for (; e + 768 < e1; e += 1024) {
      int d0 = dst[e];
      int d1 = dst[e + 256];
      int d2 = dst[e + 512];
      int d3 = dst[e + 768];
      if ((unsigned)(d0 - nbase) < (unsigned)cw) atomicAdd(&lh[d0 - nbase], 1);
      if ((unsigned)(d1 - nbase) < (unsigned)cw) atomicAdd(&lh[d1 - nbase], 1);
      if ((unsigned)(d2 - nbase) < (unsigned)cw) atomicAdd(&lh[d2 - nbase], 1);
      if ((unsigned)(d3 - nbase) < (unsigned)cw) atomicAdd(&lh[d3 - nbase], 1);
    }
    for (; e < e1; e += 256) {
      int d = dst[e];
      if ((unsigned)(d - nbase) < (unsigned)cw) atomicAdd(&lh[d - nbase], 1);
    }
    __syncthreads();
    ushort_t* prow = partials + (size_t)(cls * HIST_H + h) * cwp;
    for (int j = threadIdx.x; j < cw; j += 256) prow[j] = (ushort_t)lh[j];
    return;
  }
  // ---- MFMA GEMM path ----
  const int t = threadIdx.x;
  const int wv = t >> 6;  // wave 0..3
  const int l = t & 63;
  const int g = l >> 4;   // lane group 0..3
  const int lm = l & 15;
  const int arow = blockIdx.x * 64 + wv * 16 + lm;
  const int arowc = min(arow, N - 1);  // clamp OOB loads (rows independent)

  f32x4 acc[8];
#pragma unroll
  for (int nt = 0; nt < 8; nt++) acc[nt] = (f32x4){0.f, 0.f, 0.f, 0.f};

#pragma unroll
  for (int kt = 0; kt < 4; kt++) {
    const float* ap = feat + (size_t)arowc * F + kt * 32 + g * 8;
    float a[8];
    *(float4*)&a[0] = *(const float4*)ap;
    *(float4*)&a[4] = *(const float4*)(ap + 4);
    short8 ahi, alo;
#pragma unroll
    for (int j = 0; j < 8; j++) {
      unsigned u = __float_as_uint(a[j]);
      unsigned hb2 = u & 0xFFFF0000u;
      float lo = a[j] - __uint_as_float(hb2);
      ahi[j] = (short)(hb2 >> 16);
      alo[j] = (short)f2bf(lo);
    }
    const ushort_t* bh = whi + (size_t)(kt * 8) * 512 + l * 8;  // frag=512 sh
    const ushort_t* bl = wlo + (size_t)(kt * 8) * 512 + l * 8;
#pragma unroll
    for (int nt = 0; nt < 8; nt++) {
      short8 bhi = *(const short8*)(bh + nt * 512);
      short8 blo = *(const short8*)(bl + nt * 512);
      acc[nt] =
          __builtin_amdgcn_mfma_f32_16x16x32_bf16(ahi, blo, acc[nt], 0, 0, 0);
      acc[nt] =
          __builtin_amdgcn_mfma_f32_16x16x32_bf16(alo, bhi, acc[nt], 0, 0, 0);
      acc[nt] =
          __builtin_amdgcn_mfma_f32_16x16x32_bf16(ahi, bhi, acc[nt], 0, 0, 0);
    }
  }

  // epilogue: C/D layout col = lane&15, row = (lane>>4)*4 + reg (m89-verified)
  const int orow0 = blockIdx.x * 64 + wv * 16 + g * 4;
#pragma unroll
  for (int reg = 0; reg < 4; reg++) {
    int orow = orow0 + reg;
    if (orow < N) {
#pragma unroll
      for (int nt = 0; nt < 8; nt++)
        ftb[(size_t)orow * F + nt * 16 + lm] = f2bf(acc[nt][reg]);
    }
  }
}

// ---------------------------------------------------------------------------
// K3: single-pass scan with decoupled lookback.
// Per node: total = sum_h partials16; global exclusive prefix -> offs
// (+ sentinel offs[N] = E); relative u16 segment cursors -> rel16.
// bstate[b] packs (flag<<32 | inclusive-or-aggregate sum); flag 1=AGG 2=PFX.
// Grid (<=256 blocks) is fully co-resident -> lookback cannot deadlock.
// ---------------------------------------------------------------------------
__global__ __launch_bounds__(256) void scan_kernel(
    const ushort_t* __restrict__ partials, int cwp, int* __restrict__ offs,
    ushort_t* __restrict__ rel16, u64_t* __restrict__ bstate, int N) {
  __shared__ int s[256];
  __shared__ int sprefix;
  const int t = threadIdx.x, b = blockIdx.x;
  const int i = b * 256 + t;
  const int cw = (N + 7) >> 3;
  int v = 0;
  int c = 0, j = 0;
  if (i < N) {
    c = i / cw;
    j = i - c * cw;
    const ushort_t* base = partials + (size_t)c * HIST_H * cwp + j;
#pragma unroll 8
    for (int h = 0; h < HIST_H; h++) v += base[(size_t)h * cwp];
  }
  s[t] = v;
  __syncthreads();
  for (int d = 1; d < 256; d <<= 1) {
    int x = (t >= d) ? s[t - d] : 0;
    __syncthreads();
    s[t] += x;
    __syncthreads();
  }
  const int incl = s[t];    // inclusive prefix within block
  const int bsum = s[255];  // block total
  if (t == 0) {
    atomicExch(&bstate[b], (1ULL << 32) | (unsigned)bsum);  // publish AGG
    int pfx = 0;
    for (int pb = b - 1; pb >= 0; pb--) {
      u64_t st;
      do {
        st = atomicAdd(&bstate[pb], 0ULL);  // device-scope atomic read
      } while ((st >> 32) == 0);
      pfx += (int)(unsigned)st;
      if ((st >> 32) == 2ULL) break;
    }
    atomicExch(&bstate[b], (2ULL << 32) | (unsigned)(pfx + bsum));  // PFX
    sprefix = pfx;
  }
  __syncthreads();
  if (i < N) {
    const int o = sprefix + incl - v;  // global exclusive prefix
    offs[i] = o;
    if (i == N - 1) offs[N] = o + v;  // sentinel = E
    const ushort_t* pb2 = partials + (size_t)c * HIST_H * cwp + j;
    ushort_t* cb = rel16 + (size_t)c * HIST_H * cwp + j;
    int run = 0;
#pragma unroll 8
    for (int h = 0; h < HIST_H; h++) {
      cb[(size_t)h * cwp] = (ushort_t)run;
      run += pb2[(size_t)h * cwp];
    }
  }
}

// ---------------------------------------------------------------------------
// K4: scatter, zero global atomics. Block (cls,h): lcur[j] = offs[nbase+j]
// (L2-broadcast within the class's same-XCD blocks) + rel16 row; rescans
// segment h (4-deep batched), LDS-atomicAdd -> exact csr slot. csr lines of
// a class owned by one XCD (bid&7) -> stores merge in L2.
// ---------------------------------------------------------------------------
__global__ __launch_bounds__(256) void scatter_kernel(
    const int* __restrict__ src, const int* __restrict__ dst,
    const int* __restrict__ offs, const ushort_t* __restrict__ rel16, int cwp,
    int* __restrict__ csr, int E, int N) {
  __shared__ int lcur[CW_MAX];
  const int cls = blockIdx.x & 7;
  const int h = blockIdx.x >> 3;
  const int cw = (N + 7) >> 3;
  const int nbase = cls * cw;
  const int jmax = min(cw, N - nbase);
  const ushort_t* crow = rel16 + (size_t)(cls * HIST_H + h) * cwp;
  for (int j = threadIdx.x; j < jmax; j += 256)
    lcur[j] = offs[nbase + j] + (int)crow[j];
  __syncthreads();
  const int seg = (E + HIST_H - 1) / HIST_H;
  const int e0 = h * seg;
  const int e1 = min(e0 + seg, E);
  int e = e0 + (int)threadIdx.x;
  for (; e + 768 < e1; e += 1024) {
    int d0 = dst[e];
    int d1 = dst[e + 256];
    int d2 = dst[e + 512];
    int d3 = dst[e + 768];
    int s0 = src[e];
    int s1 = src[e + 256];
    int s2 = src[e + 512];
    int s3 = src[e + 768];
    if ((unsigned)(d0 - nbase) < (unsigned)cw)
      csr[atomicAdd(&lcur[d0 - nbase], 1)] = s0;
    if ((unsigned)(d1 - nbase) < (unsigned)cw)
      csr[atomicAdd(&lcur[d1 - nbase], 1)] = s1;
    if ((unsigned)(d2 - nbase) < (unsigned)cw)
      csr[atomicAdd(&lcur[d2 - nbase], 1)] = s2;
    if ((unsigned)(d3 - nbase) < (unsigned)cw)
      csr[atomicAdd(&lcur[d3 - nbase], 1)] = s3;
  }
  for (; e < e1; e += 256) {
    int d = dst[e];
    int sv = src[e];
    if ((unsigned)(d - nbase) < (unsigned)cw)
      csr[atomicAdd(&lcur[d - nbase], 1)] = sv;
  }
}

// ---------------------------------------------------------------------------
// K5: fused per-node online-softmax aggregation, bf16 ft, 8-deep pipelined.
// 4 lanes per (node, head), 8 dims/lane. deg = offs[n+1]-offs[n].
// ---------------------------------------------------------------------------
__global__ __launch_bounds__(256) void aggregate_kernel(
    const ushort_t* __restrict__ ftb, const int* __restrict__ offs,
    const int* __restrict__ csr, const float* __restrict__ bias,
    float* __restrict__ out, int N) {
  const int T = blockIdx.x * 256 + threadIdx.x;
  if (T >= N * 16) return;
  const int sub = T & 3;  // quarter of a head's D
  const int p = T >> 2;   // (node, head)
  const int h = p & 3;
  const int n = p >> 2;
  const int dimBase = h * DHEAD + sub * 8;

  const int off = offs[n];
  const int deg = offs[n + 1] - off;

  float ftd[8];
  {
    int4 r = *(const int4*)&ftb[n * F + dimBase];
    unpack8(r, ftd);
  }

  const float LOG2E = 1.4426950408889634f;
  float m = -INFINITY, s = 0.f;
  float acc[8];
#pragma unroll
  for (int j = 0; j < 8; j++) acc[j] = 0.f;

#define PROCESS(RX)                                              \
  do {                                                           \
    float v[8];                                                  \
    unpack8(RX, v);                                              \
    float part = 0.f;                                            \
    _Pragma("unroll") for (int j = 0; j < 8; j++) part =         \
        fmaf(ftd[j], v[j], part);                                \
    part += __shfl_xor(part, 1, 4);                              \
    part += __shfl_xor(part, 2, 4);                              \
    float el = part * LOG2E;                                     \
    float mn = fmaxf(m, el);                                     \
    float scale = exp2f(m - mn);                                 \
    float w = exp2f(el - mn);                                    \
    s = fmaf(s, scale, w);                                       \
    _Pragma("unroll") for (int j = 0; j < 8; j++) acc[j] =       \
        fmaf(acc[j], scale, w * v[j]);                           \
    m = mn;                                                      \
  } while (0)

  int4 R0 = make_int4(0, 0, 0, 0), R1 = R0, R2 = R0, R3 = R0;
  int4 R4 = R0, R5 = R0, R6 = R0, R7 = R0;
  if (deg > 0) {
    int dm1 = deg - 1;
    int s0 = csr[off];
    int s1 = csr[off + min(1, dm1)];
    int s2 = csr[off + min(2, dm1)];
    int s3 = csr[off + min(3, dm1)];
    int s4 = csr[off + min(4, dm1)];
    int s5 = csr[off + min(5, dm1)];
    int s6 = csr[off + min(6, dm1)];
    int s7 = csr[off + min(7, dm1)];
    R0 = *(const int4*)&ftb[s0 * F + dimBase];
    R1 = *(const int4*)&ftb[s1 * F + dimBase];
    R2 = *(const int4*)&ftb[s2 * F + dimBase];
    R3 = *(const int4*)&ftb[s3 * F + dimBase];
    R4 = *(const int4*)&ftb[s4 * F + dimBase];
    R5 = *(const int4*)&ftb[s5 * F + dimBase];
    R6 = *(const int4*)&ftb[s6 * F + dimBase];
    R7 = *(const int4*)&ftb[s7 * F + dimBase];
  }
  int i = 0;
  for (; i + 8 <= deg; i += 8) {
    // branchless 8-ahead prefetch (clamped; duplicate loads are cache hits)
    int dm1 = deg - 1;
    int sa = csr[off + min(i + 8, dm1)];
    int sb = csr[off + min(i + 9, dm1)];
    int sc = csr[off + min(i + 10, dm1)];
    int sd = csr[off + min(i + 11, dm1)];
    int se = csr[off + min(i + 12, dm1)];
    int sf = csr[off + min(i + 13, dm1)];
    int sg = csr[off + min(i + 14, dm1)];
    int sh = csr[off + min(i + 15, dm1)];
    int4 Na = *(const int4*)&ftb[sa * F + dimBase];
    int4 Nb = *(const int4*)&ftb[sb * F + dimBase];
    int4 Nc = *(const int4*)&ftb[sc * F + dimBase];
    int4 Nd = *(const int4*)&ftb[sd * F + dimBase];
    int4 Ne = *(const int4*)&ftb[se * F + dimBase];
    int4 Nf = *(const int4*)&ftb[sf * F + dimBase];
    int4 Ng = *(const int4*)&ftb[sg * F + dimBase];
    int4 Nh = *(const int4*)&ftb[sh * F + dimBase];
    PROCESS(R0);
    PROCESS(R1);
    PROCESS(R2);
    PROCESS(R3);
    PROCESS(R4);
    PROCESS(R5);
    PROCESS(R6);
    PROCESS(R7);
    R0 = Na; R1 = Nb; R2 = Nc; R3 = Nd;
    R4 = Ne; R5 = Nf; R6 = Ng; R7 = Nh;
  }
  int r = deg - i;  // 0..7 remaining, already resident in R0..R6
  if (r > 0) PROCESS(R0);
  if (r > 1) PROCESS(R1);
  if (r > 2) PROCESS(R2);
  if (r > 3) PROCESS(R3);
  if (r > 4) PROCESS(R4);
  if (r > 5) PROCESS(R5);
  if (r > 6) PROCESS(R6);
#undef PROCESS

  float inv = (deg > 0) ? 1.f / s : 0.f;  // deg==0 -> out = bias
  float4 b0 = *(const float4*)&bias[dimBase];
  float4 b1 = *(const float4*)&bias[dimBase + 4];
  f32x4 o0 = {acc[0] * inv + b0.x, acc[1] * inv + b0.y, acc[2] * inv + b0.z,
              acc[3] * inv + b0.w};
  f32x4 o1 = {acc[4] * inv + b1.x, acc[5] * inv + b1.y, acc[6] * inv + b1.z,
              acc[7] * inv + b1.w};
  // out has no reuse: nontemporal stores keep L2 for the ftb gather
  __builtin_nontemporal_store(o0, (f32x4*)&out[n * F + dimBase]);
  __builtin_nontemporal_store(o1, (f32x4*)&out[n * F + dimBase + 4]);
}

// ---------------------------------------------------------------------------
extern "C" void kernel_launch(void* const* d_in, const int* in_sizes, int n_in,
                              void* d_out, int out_size, void* d_ws,
                              size_t ws_size, hipStream_t stream) {
  const float* feat = (const float*)d_in[0];
  const int* src = (const int*)d_in[1];
  const int* dst = (const int*)d_in[2];
  const float* W = (const float*)d_in[3];
  const float* bias = (const float*)d_in[4];
  float* out = (float*)d_out;

  const int N = in_sizes[0] / F;
  const int E = in_sizes[1];
  const int cw = (N + 7) >> 3;      // nodes per class (<= CW_MAX)
  const int cwp = (cw + 31) & ~31;  // padded u16 row (64B aligned)

  // workspace layout (~43 MB used)
  char* ws = (char*)d_ws;
  ushort_t* ftb = (ushort_t*)ws;  // N*128 bf16 = 12.8 MB
  size_t ftB = (size_t)N * F * sizeof(ushort_t);
  ftB = (ftB + 255) & ~(size_t)255;
  int* offs = (int*)(ws + ftB);                   // N+1
  int* csr = offs + N + 1;                        // E
  ushort_t* whi = (ushort_t*)(csr + E);           // 16384 shorts (32 KB)
  ushort_t* wlo = whi + 128 * 128;                // 16384 shorts (32 KB)
  ushort_t* partials = wlo + 128 * 128;           // 8*HIST_H*cwp u16 (12.9MB)
  ushort_t* rel16 = partials + 8 * HIST_H * cwp;  // 8*HIST_H*cwp u16 (12.9MB)
  size_t relEnd = (size_t)(rel16 + 8 * HIST_H * cwp - (ushort_t*)ws);
  u64_t* bstate = (u64_t*)(ws + ((relEnd * 2 + 7) & ~(size_t)7));  // 256 u64

  wprep_kernel<<<64, 256, 0, stream>>>(W, whi, wlo, bstate);

  int gemmBlocks = (N + 63) / 64;
  gemm_hist_kernel<<<gemmBlocks + 8 * HIST_H, 256, 0, stream>>>(
      feat, whi, wlo, ftb, N, dst, partials, cwp, E, gemmBlocks);

  int nb = (N + 255) / 256;  // 196 for N=50000 (must be <= 256)
  scan_kernel<<<nb, 256, 0, stream>>>(partials, cwp, offs, rel16, bstate, N);

  scatter_kernel<<<8 * HIST_H, 256, 0, stream>>>(src, dst, offs, rel16, cwp,
                                                 csr, E, N);

  aggregate_kernel<<<(N * 16 + 255) / 256, 256, 0, stream>>>(ftb, offs, csr,
                                                             bias, out, N);
}

// Round 11
// 88.782 us; speedup vs baseline: 1.1509x; 1.1509x over previous
//
#include <hip/hip_runtime.h>
#include <math.h>

#define F 128
#define HEADS 4
#define DHEAD 32
#define HIST_H 128         // segments per class; 8*HIST_H hist/scatter blocks
#define CW_MAX 6592        // max nodes per class (LDS cap); N <= 52736

typedef unsigned short ushort_t;
typedef __attribute__((ext_vector_type(8))) short short8;   // 8 bf16 (4 VGPR)
typedef __attribute__((ext_vector_type(4))) float f32x4;    // MFMA acc

// round-to-nearest-even fp32 -> bf16
__device__ __forceinline__ ushort_t f2bf(float x) {
  unsigned u = __float_as_uint(x);
  unsigned r = u + 0x7FFFu + ((u >> 16) & 1u);
  return (ushort_t)(r >> 16);
}

// unpack 8 packed bf16 (as int4) -> 8 fp32
__device__ __forceinline__ void unpack8(const int4& r, float* v) {
  int rr[4] = {r.x, r.y, r.z, r.w};
#pragma unroll
  for (int q = 0; q < 4; q++) {
    unsigned u = (unsigned)rr[q];
    v[2 * q] = __uint_as_float(u << 16);
    v[2 * q + 1] = __uint_as_float(u & 0xFFFF0000u);
  }
}

// ---------------------------------------------------------------------------
// K-1: pack W (128x128 fp32) into MFMA-fragment-ordered bf16 hi/lo arrays.
// ---------------------------------------------------------------------------
__global__ __launch_bounds__(256) void wprep_kernel(
    const float* __restrict__ W, ushort_t* __restrict__ whi,
    ushort_t* __restrict__ wlo) {
  int idx = blockIdx.x * 256 + threadIdx.x;  // 0..16383
  if (idx >= 128 * 128) return;
  int j = idx & 7;
  int lane = (idx >> 3) & 63;
  int f = idx >> 9;  // kt*8+nt
  int kt = f >> 3, nt = f & 7;
  int k = kt * 32 + (lane >> 4) * 8 + j;
  int n = nt * 16 + (lane & 15);
  float w = W[k * 128 + n];
  unsigned u = __float_as_uint(w);
  unsigned hb = u & 0xFFFF0000u;
  float lo = w - __uint_as_float(hb);
  whi[idx] = (ushort_t)(hb >> 16);
  wlo[idx] = f2bf(lo);
}

// ---------------------------------------------------------------------------
// K1: fused  [0..gemmBlocks): ft = feat @ W via split-precision bf16 MFMA
//            [gemmBlocks..+8*HIST_H): LDS partial histograms -> u16 partials.
// ---------------------------------------------------------------------------
__global__ __launch_bounds__(256) void gemm_hist_kernel(
    const float* __restrict__ feat, const ushort_t* __restrict__ whi,
    const ushort_t* __restrict__ wlo, ushort_t* __restrict__ ftb, int N,
    const int* __restrict__ dst, ushort_t* __restrict__ partials, int cwp,
    int E, int gemmBlocks) {
  __shared__ int lh[CW_MAX];
  if ((int)blockIdx.x >= gemmBlocks) {
    // ---- partial histogram path (LDS atomics only) ----
    const int hb = blockIdx.x - gemmBlocks;
    const int cls = hb & 7;
    const int h = hb >> 3;
    const int cw = (N + 7) >> 3;
    const int nbase = cls * cw;
    for (int j = threadIdx.x; j < cw; j += 256) lh[j] = 0;
    __syncthreads();
    const int seg = (E + HIST_H - 1) / HIST_H;
    const int e0 = h * seg;
    const int e1 = min(e0 + seg, E);
    int e = e0 + (int)threadIdx.x;
    for (; e + 768 < e1; e += 1024) {
      int d0 = dst[e];
      int d1 = dst[e + 256];
      int d2 = dst[e + 512];
      int d3 = dst[e + 768];
      if ((unsigned)(d0 - nbase) < (unsigned)cw) atomicAdd(&lh[d0 - nbase], 1);
      if ((unsigned)(d1 - nbase) < (unsigned)cw) atomicAdd(&lh[d1 - nbase], 1);
      if ((unsigned)(d2 - nbase) < (unsigned)cw) atomicAdd(&lh[d2 - nbase], 1);
      if ((unsigned)(d3 - nbase) < (unsigned)cw) atomicAdd(&lh[d3 - nbase], 1);
    }
    for (; e < e1; e += 256) {
      int d = dst[e];
      if ((unsigned)(d - nbase) < (unsigned)cw) atomicAdd(&lh[d - nbase], 1);
    }
    __syncthreads();
    ushort_t* prow = partials + (size_t)(cls * HIST_H + h) * cwp;
    for (int j = threadIdx.x; j < cw; j += 256) prow[j] = (ushort_t)lh[j];
    return;
  }
  // ---- MFMA GEMM path ----
  const int t = threadIdx.x;
  const int wv = t >> 6;  // wave 0..3
  const int l = t & 63;
  const int g = l >> 4;   // lane group 0..3
  const int lm = l & 15;
  const int arow = blockIdx.x * 64 + wv * 16 + lm;
  const int arowc = min(arow, N - 1);  // clamp OOB loads (rows independent)

  f32x4 acc[8];
#pragma unroll
  for (int nt = 0; nt < 8; nt++) acc[nt] = (f32x4){0.f, 0.f, 0.f, 0.f};

#pragma unroll
  for (int kt = 0; kt < 4; kt++) {
    const float* ap = feat + (size_t)arowc * F + kt * 32 + g * 8;
    float a[8];
    *(float4*)&a[0] = *(const float4*)ap;
    *(float4*)&a[4] = *(const float4*)(ap + 4);
    short8 ahi, alo;
#pragma unroll
    for (int j = 0; j < 8; j++) {
      unsigned u = __float_as_uint(a[j]);
      unsigned hb2 = u & 0xFFFF0000u;
      float lo = a[j] - __uint_as_float(hb2);
      ahi[j] = (short)(hb2 >> 16);
      alo[j] = (short)f2bf(lo);
    }
    const ushort_t* bh = whi + (size_t)(kt * 8) * 512 + l * 8;  // frag=512 sh
    const ushort_t* bl = wlo + (size_t)(kt * 8) * 512 + l * 8;
#pragma unroll
    for (int nt = 0; nt < 8; nt++) {
      short8 bhi = *(const short8*)(bh + nt * 512);
      short8 blo = *(const short8*)(bl + nt * 512);
      acc[nt] =
          __builtin_amdgcn_mfma_f32_16x16x32_bf16(ahi, blo, acc[nt], 0, 0, 0);
      acc[nt] =
          __builtin_amdgcn_mfma_f32_16x16x32_bf16(alo, bhi, acc[nt], 0, 0, 0);
      acc[nt] =
          __builtin_amdgcn_mfma_f32_16x16x32_bf16(ahi, bhi, acc[nt], 0, 0, 0);
    }
  }

  // epilogue: C/D layout col = lane&15, row = (lane>>4)*4 + reg (m89-verified)
  const int orow0 = blockIdx.x * 64 + wv * 16 + g * 4;
#pragma unroll
  for (int reg = 0; reg < 4; reg++) {
    int orow = orow0 + reg;
    if (orow < N) {
#pragma unroll
      for (int nt = 0; nt < 8; nt++)
        ftb[(size_t)orow * F + nt * 16 + lm] = f2bf(acc[nt][reg]);
    }
  }
}

// ---------------------------------------------------------------------------
// K3a: single pass over partials: emits rel16 (relative segment cursors,
// which do NOT depend on the global offset), node totals -> block-local
// exclusive prefix into offs + per-block sums.
// ---------------------------------------------------------------------------
__global__ void scan_block_kernel(const ushort_t* __restrict__ partials,
                                  int cwp, int* __restrict__ offs,
                                  ushort_t* __restrict__ rel16,
                                  int* __restrict__ bsums, int N) {
  __shared__ int s[256];
  int t = threadIdx.x, i = blockIdx.x * 256 + t;
  int v = 0;
  if (i < N) {
    int cw = (N + 7) >> 3;
    int c = i / cw;
    int j = i - c * cw;
    const ushort_t* pb = partials + (size_t)c * HIST_H * cwp + j;
    ushort_t* cb = rel16 + (size_t)c * HIST_H * cwp + j;
    int run = 0;
#pragma unroll 8
    for (int h = 0; h < HIST_H; h++) {
      cb[(size_t)h * cwp] = (ushort_t)run;
      run += pb[(size_t)h * cwp];
    }
    v = run;  // node total degree
  }
  s[t] = v;
  __syncthreads();
  for (int d = 1; d < 256; d <<= 1) {
    int x = (t >= d) ? s[t - d] : 0;
    __syncthreads();
    s[t] += x;
    __syncthreads();
  }
  if (i < N) offs[i] = s[t] - v;  // block-local exclusive
  if (t == 255) bsums[blockIdx.x] = s[255];
}

// K3b: finish offs with block-sum prefix; write sentinel offs[N] = E.
__global__ void scan_finish_kernel(int* __restrict__ offs,
                                   const int* __restrict__ bsums, int N,
                                   int E) {
  int t = threadIdx.x, b = blockIdx.x;
  int v = (t < b) ? bsums[t] : 0;  // nb <= 256 guaranteed
#pragma unroll
  for (int d = 32; d > 0; d >>= 1) v += __shfl_down(v, d, 64);
  __shared__ int wsum[4];
  if ((t & 63) == 0) wsum[t >> 6] = v;
  __syncthreads();
  int total = wsum[0] + wsum[1] + wsum[2] + wsum[3];
  int i = b * 256 + t;
  if (i < N) offs[i] += total;
  if (b == 0 && t == 0) offs[N] = E;  // sentinel
}

// ---------------------------------------------------------------------------
// K4: scatter, zero global atomics. Block (cls,h): lcur[j] = offs[nbase+j]
// (L2-broadcast within the class's same-XCD blocks) + rel16 row; rescans
// segment h (4-deep batched), LDS-atomicAdd -> exact csr slot. csr lines of
// a class owned by one XCD (bid&7) -> stores merge in L2.
// ---------------------------------------------------------------------------
__global__ __launch_bounds__(256) void scatter_kernel(
    const int* __restrict__ src, const int* __restrict__ dst,
    const int* __restrict__ offs, const ushort_t* __restrict__ rel16, int cwp,
    int* __restrict__ csr, int E, int N) {
  __shared__ int lcur[CW_MAX];
  const int cls = blockIdx.x & 7;
  const int h = blockIdx.x >> 3;
  const int cw = (N + 7) >> 3;
  const int nbase = cls * cw;
  const int jmax = min(cw, N - nbase);
  const ushort_t* crow = rel16 + (size_t)(cls * HIST_H + h) * cwp;
  for (int j = threadIdx.x; j < jmax; j += 256)
    lcur[j] = offs[nbase + j] + (int)crow[j];
  __syncthreads();
  const int seg = (E + HIST_H - 1) / HIST_H;
  const int e0 = h * seg;
  const int e1 = min(e0 + seg, E);
  int e = e0 + (int)threadIdx.x;
  for (; e + 768 < e1; e += 1024) {
    int d0 = dst[e];
    int d1 = dst[e + 256];
    int d2 = dst[e + 512];
    int d3 = dst[e + 768];
    int s0 = src[e];
    int s1 = src[e + 256];
    int s2 = src[e + 512];
    int s3 = src[e + 768];
    if ((unsigned)(d0 - nbase) < (unsigned)cw)
      csr[atomicAdd(&lcur[d0 - nbase], 1)] = s0;
    if ((unsigned)(d1 - nbase) < (unsigned)cw)
      csr[atomicAdd(&lcur[d1 - nbase], 1)] = s1;
    if ((unsigned)(d2 - nbase) < (unsigned)cw)
      csr[atomicAdd(&lcur[d2 - nbase], 1)] = s2;
    if ((unsigned)(d3 - nbase) < (unsigned)cw)
      csr[atomicAdd(&lcur[d3 - nbase], 1)] = s3;
  }
  for (; e < e1; e += 256) {
    int d = dst[e];
    int sv = src[e];
    if ((unsigned)(d - nbase) < (unsigned)cw)
      csr[atomicAdd(&lcur[d - nbase], 1)] = sv;
  }
}

// ---------------------------------------------------------------------------
// K5: fused per-node online-softmax aggregation, bf16 ft, 4-deep pipelined.
// 4 lanes per (node, head), 8 dims/lane. deg = offs[n+1]-offs[n].
// ---------------------------------------------------------------------------
__global__ __launch_bounds__(256) void aggregate_kernel(
    const ushort_t* __restrict__ ftb, const int* __restrict__ offs,
    const int* __restrict__ csr, const float* __restrict__ bias,
    float* __restrict__ out, int N) {
  const int T = blockIdx.x * 256 + threadIdx.x;
  if (T >= N * 16) return;
  const int sub = T & 3;  // quarter of a head's D
  const int p = T >> 2;   // (node, head)
  const int h = p & 3;
  const int n = p >> 2;
  const int dimBase = h * DHEAD + sub * 8;

  const int off = offs[n];
  const int deg = offs[n + 1] - off;

  float ftd[8];
  {
    int4 r = *(const int4*)&ftb[n * F + dimBase];
    unpack8(r, ftd);
  }

  const float LOG2E = 1.4426950408889634f;
  float m = -INFINITY, s = 0.f;
  float acc[8];
#pragma unroll
  for (int j = 0; j < 8; j++) acc[j] = 0.f;

#define PROCESS(RX)                                              \
  do {                                                           \
    float v[8];                                                  \
    unpack8(RX, v);                                              \
    float part = 0.f;                                            \
    _Pragma("unroll") for (int j = 0; j < 8; j++) part =         \
        fmaf(ftd[j], v[j], part);                                \
    part += __shfl_xor(part, 1, 4);                              \
    part += __shfl_xor(part, 2, 4);                              \
    float el = part * LOG2E;                                     \
    float mn = fmaxf(m, el);                                     \
    float scale = exp2f(m - mn);                                 \
    float w = exp2f(el - mn);                                    \
    s = fmaf(s, scale, w);                                       \
    _Pragma("unroll") for (int j = 0; j < 8; j++) acc[j] =       \
        fmaf(acc[j], scale, w * v[j]);                           \
    m = mn;                                                      \
  } while (0)

  int4 R0 = make_int4(0, 0, 0, 0), R1 = R0, R2 = R0, R3 = R0;
  if (deg > 0) {
    int dm1 = deg - 1;
    int s0 = csr[off];
    int s1 = csr[off + min(1, dm1)];
    int s2 = csr[off + min(2, dm1)];
    int s3 = csr[off + min(3, dm1)];
    R0 = *(const int4*)&ftb[s0 * F + dimBase];
    R1 = *(const int4*)&ftb[s1 * F + dimBase];
    R2 = *(const int4*)&ftb[s2 * F + dimBase];
    R3 = *(const int4*)&ftb[s3 * F + dimBase];
  }
  int i = 0;
  for (; i + 4 <= deg; i += 4) {
    // branchless 4-ahead prefetch (clamped; duplicate loads are cache hits)
    int dm1 = deg - 1;
    int sa = csr[off + min(i + 4, dm1)];
    int sb = csr[off + min(i + 5, dm1)];
    int sc = csr[off + min(i + 6, dm1)];
    int sd = csr[off + min(i + 7, dm1)];
    int4 Na = *(const int4*)&ftb[sa * F + dimBase];
    int4 Nb = *(const int4*)&ftb[sb * F + dimBase];
    int4 Nc = *(const int4*)&ftb[sc * F + dimBase];
    int4 Nd = *(const int4*)&ftb[sd * F + dimBase];
    PROCESS(R0);
    PROCESS(R1);
    PROCESS(R2);
    PROCESS(R3);
    R0 = Na; R1 = Nb; R2 = Nc; R3 = Nd;
  }
  int r = deg - i;  // 0..3 remaining, already resident in R0..R2
  if (r > 0) PROCESS(R0);
  if (r > 1) PROCESS(R1);
  if (r > 2) PROCESS(R2);
#undef PROCESS

  float inv = (deg > 0) ? 1.f / s : 0.f;  // deg==0 -> out = bias
  float4 b0 = *(const float4*)&bias[dimBase];
  float4 b1 = *(const float4*)&bias[dimBase + 4];
  f32x4 o0 = {acc[0] * inv + b0.x, acc[1] * inv + b0.y, acc[2] * inv + b0.z,
              acc[3] * inv + b0.w};
  f32x4 o1 = {acc[4] * inv + b1.x, acc[5] * inv + b1.y, acc[6] * inv + b1.z,
              acc[7] * inv + b1.w};
  // out has no reuse: nontemporal stores keep L2 for the ftb gather
  __builtin_nontemporal_store(o0, (f32x4*)&out[n * F + dimBase]);
  __builtin_nontemporal_store(o1, (f32x4*)&out[n * F + dimBase + 4]);
}

// ---------------------------------------------------------------------------
extern "C" void kernel_launch(void* const* d_in, const int* in_sizes, int n_in,
                              void* d_out, int out_size, void* d_ws,
                              size_t ws_size, hipStream_t stream) {
  const float* feat = (const float*)d_in[0];
  const int* src = (const int*)d_in[1];
  const int* dst = (const int*)d_in[2];
  const float* W = (const float*)d_in[3];
  const float* bias = (const float*)d_in[4];
  float* out = (float*)d_out;

  const int N = in_sizes[0] / F;
  const int E = in_sizes[1];
  const int cw = (N + 7) >> 3;      // nodes per class (<= CW_MAX)
  const int cwp = (cw + 31) & ~31;  // padded u16 row (64B aligned)

  // workspace layout (~43 MB used)
  char* ws = (char*)d_ws;
  ushort_t* ftb = (ushort_t*)ws;  // N*128 bf16 = 12.8 MB
  size_t ftB = (size_t)N * F * sizeof(ushort_t);
  ftB = (ftB + 255) & ~(size_t)255;
  int* offs = (int*)(ws + ftB);                   // N+1
  int* bsums = offs + N + 1;                      // 256
  int* csr = bsums + 256;                         // E
  ushort_t* whi = (ushort_t*)(csr + E);           // 16384 shorts (32 KB)
  ushort_t* wlo = whi + 128 * 128;                // 16384 shorts (32 KB)
  ushort_t* partials = wlo + 128 * 128;           // 8*HIST_H*cwp u16 (12.9MB)
  ushort_t* rel16 = partials + 8 * HIST_H * cwp;  // 8*HIST_H*cwp u16 (12.9MB)

  wprep_kernel<<<64, 256, 0, stream>>>(W, whi, wlo);

  int gemmBlocks = (N + 63) / 64;
  gemm_hist_kernel<<<gemmBlocks + 8 * HIST_H, 256, 0, stream>>>(
      feat, whi, wlo, ftb, N, dst, partials, cwp, E, gemmBlocks);

  int nb = (N + 255) / 256;  // 196 for N=50000 (must be <= 256)
  scan_block_kernel<<<nb, 256, 0, stream>>>(partials, cwp, offs, rel16,
                                            bsums, N);
  scan_finish_kernel<<<nb, 256, 0, stream>>>(offs, bsums, N, E);

  scatter_kernel<<<8 * HIST_H, 256, 0, stream>>>(src, dst, offs, rel16, cwp,
                                                 csr, E, N);

  aggregate_kernel<<<(N * 16 + 255) / 256, 256, 0, stream>>>(ftb, offs, csr,
                                                             bias, out, N);
}